// Round 10
// baseline (86.159 us; speedup 1.0000x reference)
//
#include <hip/hip_runtime.h>
#include <hip/hip_bf16.h>
#include <math.h>

#define HW_   65536
#define B_    2
#define Q_    100
#define C_    134
#define T_    20
#define NHUN  100
#define MT_   7            // M-tiles of 16 queries (112 >= 100)
#define KSB   128          // K-split blocks per (b,mt)
#define BKCH  512          // k per block
#define PREC  1088         // part record stride (1024 frag + 16 F + 16 P + pad)
#define NCH   2048         // 32-k chunks per batch row (65536/32)
#define NSL   64           // lab_prep k-slices per batch (1024 k each)
#define LPSL  1040         // padded LDS row stride (bf16) in lab_prep

typedef __attribute__((ext_vector_type(8))) short bf16x8;
typedef __attribute__((ext_vector_type(4))) float f32x4;

// ws layout (float units)
#define LABPS_OFF  0                    // [2][20][64]
#define CC_OFF     2560                 // [200][20] (fallback path only)
#define COST_OFF   6560                 // [200][20]
#define BASE_END   10560
#define LABF1_F   BASE_END                          // 2*2048*512 ushort = 1,048,576 floats
#define LABF2_F   (LABF1_F + 1048576)
#define PART_OFF  (LABF2_F + 1048576)               // 1792 records * 1088 floats
#define CSUM_OFF  (PART_OFF + B_ * KSB * MT_ * PREC)
#define WS_END_F  (CSUM_OFF + B_ * MT_ * 1056)

__device__ inline unsigned short f2bf(float f) {
    unsigned int u = __builtin_bit_cast(unsigned int, f);
    u += 0x7FFFu + ((u >> 16) & 1u);               // RNE
    return (unsigned short)(u >> 16);
}
__device__ inline float softplusf(float x) {
    float ax = fabsf(x);
    return fmaxf(x, 0.0f) + log1pf(expf(-ax));
}

// ---------------- K1: decimate labels -> LDS transpose -> coalesced fragment-ordered labF ----------------
// grid (B_, NSL), 256 thr. Slice = 1024 decimated k = 32 chunks.
// labF[b][ch][lane*8+e]: lane = (t&15)+16*g holds row t, k = ch*32+g*8+e (zeros for dead lanes of labF2).
__global__ __launch_bounds__(256) void lab_prep_kernel(
        const float* __restrict__ ml, unsigned short* __restrict__ labF1,
        unsigned short* __restrict__ labF2, float* __restrict__ lab_ps, int writeT) {
    int b   = blockIdx.x;
    int sl  = blockIdx.y;           // 0..63
    int tid = threadIdx.x;          // 256
    int kb  = sl * 1024;

    __shared__ unsigned short tile[T_ * LPSL];
    __shared__ float rb[4][T_];

    float acc[T_];
    int k0 = kb + tid * 4;
    int r  = k0 >> 8, c = k0 & 255;       // same (r,c) for all t
    int goff = r * 1024 + 2 * c;          // byte-contiguous across the wave
#pragma unroll
    for (int t = 0; t < T_; ++t) {
        const float* s = ml + (size_t)(b * T_ + t) * 262144 + goff;
        float4 u = *(const float4*)s;
        float4 w = *(const float4*)(s + 4);
        float v[4] = {u.x, u.z, w.x, w.z};
        acc[t] = v[0] + v[1] + v[2] + v[3];
        unsigned short h0 = f2bf(v[0]), h1 = f2bf(v[1]), h2 = f2bf(v[2]), h3 = f2bf(v[3]);
        uint2 pk;
        pk.x = (unsigned)h0 | ((unsigned)h1 << 16);
        pk.y = (unsigned)h2 | ((unsigned)h3 << 16);
        *(uint2*)(tile + t * LPSL + tid * 4) = pk;
    }
    __syncthreads();

    if (writeT) {
        unsigned short* o1 = labF1 + (size_t)(b * NCH + sl * 32) * 512;
        unsigned short* o2 = labF2 + (size_t)(b * NCH + sl * 32) * 512;
        for (int w = tid; w < 2048; w += 256) {
            int lane = w & 63;
            int chl  = w >> 6;               // 0..31
            int ts = lane & 15, g = lane >> 4;
            int kl = chl * 32 + g * 8;
            uint4 v1 = *(const uint4*)(tile + ts * LPSL + kl);
            *(uint4*)(o1 + (size_t)w * 8) = v1;
            uint4 v2 = {0u, 0u, 0u, 0u};
            if (ts < 4) v2 = *(const uint4*)(tile + (16 + ts) * LPSL + kl);
            *(uint4*)(o2 + (size_t)w * 8) = v2;
        }
    }

    int wid = tid >> 6, lane_ = tid & 63;
#pragma unroll
    for (int t = 0; t < T_; ++t) {
        float a = acc[t];
        for (int off = 32; off > 0; off >>= 1) a += __shfl_down(a, off);
        if (lane_ == 0) rb[wid][t] = a;
    }
    __syncthreads();
    if (tid < T_)
        lab_ps[(b * T_ + tid) * NSL + sl] = rb[0][tid] + rb[1][tid] + rb[2][tid] + rb[3][tid];
}

// ---------------- class cost (fallback path only) ----------------
__global__ void class_cost_kernel(const float* __restrict__ cl, const int* __restrict__ labels,
                                  float* __restrict__ cc) {
    int bq  = blockIdx.x;
    int b   = bq / Q_;
    int tid = threadIdx.x;         // 64
    __shared__ float sl[C_];
    const float* src = cl + (size_t)bq * C_;
    for (int c = tid; c < C_; c += 64) sl[c] = src[c];
    __syncthreads();
    float mx = -INFINITY;
    for (int c = tid; c < C_; c += 64) mx = fmaxf(mx, sl[c]);
    for (int off = 32; off > 0; off >>= 1) mx = fmaxf(mx, __shfl_xor(mx, off));
    float se = 0.f;
    for (int c = tid; c < C_; c += 64) se += expf(sl[c] - mx);
    for (int off = 32; off > 0; off >>= 1) se += __shfl_xor(se, off);
    float inv = 1.0f / se;
    if (tid < T_) {
        int lbl = labels[b * T_ + tid];
        cc[bq * T_ + tid] = -expf(sl[lbl] - mx) * inv;
    }
}

// ---------------- K3: fused pointwise + single-pass bf16 MFMA partials (coalesced B) ----------------
__global__ __launch_bounds__(256) void focal_mfma_kernel(
        const float* __restrict__ mq, const unsigned short* __restrict__ labF1,
        const unsigned short* __restrict__ labF2, float* __restrict__ part) {
    int idx = blockIdx.x;
    int mt  = idx % MT_;
    int rem = idx / MT_;
    int ks  = rem % KSB;
    int b   = rem / KSB;
    int tid  = threadIdx.x;
    int wave = tid >> 6, lane = tid & 63;
    int lg = lane >> 4, lr = lane & 15;

    int q = mt * 16 + lr;
    bool qok = (q < Q_);
    const float* xrow = mq + ((size_t)(b * Q_ + (qok ? q : 0)) << 16);
    int koff = ks * BKCH + wave * 128 + lg * 8;

    const unsigned short* f1base = labF1 + (size_t)(b * NCH) * 512 + lane * 8;
    const unsigned short* f2base = labF2 + (size_t)(b * NCH) * 512 + lane * 8;

    f32x4 accD0 = {0,0,0,0}, accD1 = {0,0,0,0};
    f32x4 accP0 = {0,0,0,0}, accP1 = {0,0,0,0};
    float F = 0.f, P = 0.f;

    for (int kk = 0; kk < 4; ++kk) {
        int kb = koff + kk * 32;
        float4 u0 = *(const float4*)(xrow + kb);
        float4 u1 = *(const float4*)(xrow + kb + 4);
        float xv[8] = {u0.x, u0.y, u0.z, u0.w, u1.x, u1.y, u1.z, u1.w};

        int c = ks * 16 + wave * 4 + kk;              // 32-k chunk
        bf16x8 f1 = *(const bf16x8*)(f1base + (size_t)c * 512);
        bf16x8 f2 = *(const bf16x8*)(f2base + (size_t)c * 512);

        bf16x8 dh, ph;
#pragma unroll
        for (int e = 0; e < 8; ++e) {
            float x  = xv[e];
            float ax = fabsf(x);
            float a  = __expf(-ax);
            float rr = 1.0f / (1.0f + a);
            float p  = (x >= 0.f) ? rr : a * rr;
            float om = (x >= 0.f) ? a * rr : rr;
            float l1 = __logf(1.0f + a);
            float spn = fmaxf(-x, 0.f) + l1;
            float spp = spn + x;
            float fp = 0.25f * om * om * spn;
            float fn = 0.75f * p * p * spp;
            F += fn; P += p;
            dh[e] = (short)f2bf(fp - fn);
            ph[e] = (short)f2bf(p);
        }
        accD0 = __builtin_amdgcn_mfma_f32_16x16x32_bf16(dh, f1, accD0, 0, 0, 0);
        accD1 = __builtin_amdgcn_mfma_f32_16x16x32_bf16(dh, f2, accD1, 0, 0, 0);
        accP0 = __builtin_amdgcn_mfma_f32_16x16x32_bf16(ph, f1, accP0, 0, 0, 0);
        accP1 = __builtin_amdgcn_mfma_f32_16x16x32_bf16(ph, f2, accP1, 0, 0, 0);
    }

    F += __shfl_down(F, 32); F += __shfl_down(F, 16);
    P += __shfl_down(P, 32); P += __shfl_down(P, 16);

    __shared__ float red[4][4][64][4];
    __shared__ float fpb[4][2][16];
#pragma unroll
    for (int r = 0; r < 4; ++r) {
        red[wave][0][lane][r] = accD0[r];
        red[wave][1][lane][r] = accD1[r];
        red[wave][2][lane][r] = accP0[r];
        red[wave][3][lane][r] = accP1[r];
    }
    if (lane < 16) { fpb[wave][0][lane] = F; fpb[wave][1][lane] = P; }
    __syncthreads();
    for (int e = tid; e < 1024; e += 256) {
        int f  = e >> 8;
        int l2 = (e & 255) >> 2;
        int r  = e & 3;
        part[(size_t)idx * PREC + e] =
            red[0][f][l2][r] + red[1][f][l2][r] + red[2][f][l2][r] + red[3][f][l2][r];
    }
    if (tid < 16)
        part[(size_t)idx * PREC + 1024 + tid] =
            fpb[0][0][tid] + fpb[1][0][tid] + fpb[2][0][tid] + fpb[3][0][tid];
    else if (tid < 32) {
        int l = tid - 16;
        part[(size_t)idx * PREC + 1040 + l] =
            fpb[0][1][l] + fpb[1][1][l] + fpb[2][1][l] + fpb[3][1][l];
    }
}

// ---------------- K4a: parallel K-split reduction: part -> Csum[14][1056] ----------------
__global__ __launch_bounds__(256) void reduce_part_kernel(const float* __restrict__ part,
                                                          float* __restrict__ Csum) {
    int bm   = blockIdx.x;          // 0..13
    int mt   = bm % MT_;
    int b    = bm / MT_;
    int tid  = threadIdx.x;
    int epos = tid & 31;
    int grp  = tid >> 5;            // 0..7
    int e    = blockIdx.y * 32 + epos;   // 0..1055

    const float* base = part + (size_t)((b * KSB) * MT_ + mt) * PREC + e;
    float s = 0.f;
    for (int k = 0; k < 16; ++k) {
        s += base[(size_t)(grp * 16 + k) * MT_ * PREC];
    }
    __shared__ float red[8][33];
    red[grp][epos] = s;
    __syncthreads();
    if (tid < 32) {
        float tot = 0.f;
        for (int g = 0; g < 8; ++g) tot += red[g][tid];
        Csum[(size_t)bm * 1056 + e] = tot;
    }
}

// ---------------- K4b: finalize cost from Csum + fused class-softmax ----------------
__global__ __launch_bounds__(320) void compose_kernel(
        const float* __restrict__ Csum, const float* __restrict__ cl,
        const int* __restrict__ labels, const float* __restrict__ lab_ps,
        float* __restrict__ cost) {
    int bm = blockIdx.x;
    int mt = bm % MT_;
    int b  = bm / MT_;
    int tid = threadIdx.x;     // 320
    int q0 = mt * 16;

    __shared__ float sl[16][136];
    __shared__ float mx[16], se[16];
    __shared__ int   lbl[T_];
    for (int e = tid; e < 16 * C_; e += 320) {
        int qm = e / C_, c = e % C_;
        int q = q0 + qm;
        sl[qm][c] = (q < Q_) ? cl[(size_t)(b * Q_ + q) * C_ + c] : 0.f;
    }
    if (tid < T_) lbl[tid] = labels[b * T_ + tid];
    __syncthreads();
    if (tid < 16) {
        float m = -INFINITY;
        for (int c = 0; c < C_; ++c) m = fmaxf(m, sl[tid][c]);
        float s = 0.f;
        for (int c = 0; c < C_; ++c) s += expf(sl[tid][c] - m);
        mx[tid] = m; se[tid] = s;
    }
    __syncthreads();

    int qm = tid / T_, t = tid % T_;
    int q = q0 + qm;
    if (qm < 16 && q < Q_) {
        const float* C = Csum + (size_t)bm * 1056;
        int nt   = t >> 4;
        int lane = ((qm >> 2) << 4) | (t & 15);
        int reg  = qm & 3;
        float Sd = C[(0 + nt) * 256 + lane * 4 + reg];
        float Sp = C[(2 + nt) * 256 + lane * 4 + reg];
        float F  = C[1024 + qm];
        float P  = C[1040 + qm];
        float L = 0.f;
        for (int s8 = 0; s8 < NSL; ++s8) L += lab_ps[(b * T_ + t) * NSL + s8];
        float ccv = -expf(sl[qm][lbl[t]] - mx[qm]) / se[qm];
        float cm = (Sd + F) * (1.0f / (float)HW_);
        float cd = 1.0f - (2.0f * Sp + 1.0f) / (P + L + 1.0f);
        cost[(size_t)(b * Q_ + q) * T_ + t] = cm + cd + ccv;
    }
}

// ---------------- fallback: monolithic (round-2 proven) ----------------
__global__ __launch_bounds__(1024) void mask_cost_mono_kernel(
        const float* __restrict__ mq, const float* __restrict__ ml,
        const float* __restrict__ cc, const float* __restrict__ lab_ps,
        float* __restrict__ cost) {
    int bq  = blockIdx.x;
    int b   = bq / Q_;
    int tid = threadIdx.x;
    const float* xb  = mq + (size_t)bq * HW_;
    const float* mlb = ml + (size_t)b * T_ * 262144;
    float s1[T_], s2[T_];
#pragma unroll
    for (int t = 0; t < T_; ++t) { s1[t] = 0.f; s2[t] = 0.f; }
    float F = 0.f, P = 0.f;
    for (int k = tid; k < HW_; k += 1024) {
        int i = k >> 8, j = k & 255;
        float x = xb[k];
        float p = 1.0f / (1.0f + expf(-x));
        float spn = softplusf(-x);
        float spp = softplusf(x);
        float om = 1.0f - p;
        float fp = 0.25f * om * om * spn;
        float fn = 0.75f * p * p * spp;
        F += fn; P += p;
        float diff = fp - fn;
        int off0 = i * 1024 + 2 * j;
#pragma unroll
        for (int t = 0; t < T_; ++t) {
            float lab = mlb[t * 262144 + off0];
            s1[t] = fmaf(diff, lab, s1[t]);
            s2[t] = fmaf(p,    lab, s2[t]);
        }
    }
    __shared__ float sbuf[16][42];
    int wid = tid >> 6, lane = tid & 63;
#pragma unroll
    for (int t = 0; t < T_; ++t) {
        for (int off = 32; off > 0; off >>= 1) {
            s1[t] += __shfl_down(s1[t], off);
            s2[t] += __shfl_down(s2[t], off);
        }
    }
    for (int off = 32; off > 0; off >>= 1) { F += __shfl_down(F, off); P += __shfl_down(P, off); }
    if (lane == 0) {
#pragma unroll
        for (int t = 0; t < T_; ++t) { sbuf[wid][t] = s1[t]; sbuf[wid][T_ + t] = s2[t]; }
        sbuf[wid][40] = F; sbuf[wid][41] = P;
    }
    __syncthreads();
    if (tid < T_) {
        float S1 = 0.f, S2 = 0.f, Fs = 0.f, Ps = 0.f;
        for (int w = 0; w < 16; ++w) {
            S1 += sbuf[w][tid]; S2 += sbuf[w][T_ + tid];
            Fs += sbuf[w][40];  Ps += sbuf[w][41];
        }
        float L = 0.f;
        for (int sl = 0; sl < NSL; ++sl) L += lab_ps[(b * T_ + tid) * NSL + sl];
        float cm = (S1 + Fs) * (1.0f / (float)HW_);
        float cd = 1.0f - (2.0f * S2 + 1.0f) / (Ps + L + 1.0f);
        cost[bq * T_ + tid] = cm + cd + cc[bq * T_ + tid];
    }
}

// ---------------- K5: transposed rectangular JV Hungarian, one wave, float + ballot-argmin ----------------
__global__ __launch_bounds__(64) void hungarian_kernel(const float* __restrict__ cost,
                                                       int* __restrict__ out) {
    int b    = blockIdx.x;
    int lane = threadIdx.x;

    __shared__ float csh[Q_ * T_];
    __shared__ float u[T_ + 1];
    __shared__ int   p[NHUN + 1];
    __shared__ int   way[NHUN + 1];

    for (int idx = lane; idx < Q_ * T_; idx += 64) csh[idx] = cost[b * Q_ * T_ + idx];
    for (int j = lane; j <= NHUN; j += 64) { p[j] = 0; way[j] = 0; }
    if (lane <= T_) u[lane] = 0.f;
    __syncthreads();

    const int ja = lane;            // column A (0 = virtual root on lane 0)
    const int jb = lane + 64;       // column B (valid up to 100)
    const bool jb_ok = (jb <= NHUN);
    float v_a = 0.f, v_b = 0.f;

    for (int i = 1; i <= T_; ++i) {
        if (lane == 0) p[0] = i;
        float m_a = INFINITY, m_b = INFINITY;
        bool us_a = false, us_b = false;
        __syncthreads();
        int j0 = 0;
        while (true) {
            if (ja == j0) us_a = true;
            if (jb == j0) us_b = true;
            int   i0  = p[j0];
            float ui0 = u[i0];
            bool fa = (!us_a && ja >= 1);
            bool fb = (jb_ok && !us_b);
            if (fa) {
                float cur = csh[(ja - 1) * T_ + (i0 - 1)] - ui0 - v_a;
                if (cur < m_a) { m_a = cur; way[ja] = j0; }
            }
            if (fb) {
                float cur = csh[(jb - 1) * T_ + (i0 - 1)] - ui0 - v_b;
                if (cur < m_b) { m_b = cur; way[jb] = j0; }
            }
            float ca = fa ? m_a : INFINITY;
            float cb = fb ? m_b : INFINITY;
            float vmin = fminf(ca, cb);
            for (int off = 32; off > 0; off >>= 1)
                vmin = fminf(vmin, __shfl_xor(vmin, off));
            unsigned long long ba = __ballot(ca == vmin);
            int j1;
            if (ba) j1 = __ffsll(ba) - 1;
            else    j1 = __ffsll(__ballot(cb == vmin)) - 1 + 64;
            float delta = vmin;
            if (us_a) { u[p[ja]] += delta; v_a -= delta; } else { m_a -= delta; }
            if (jb_ok) {
                if (us_b) { u[p[jb]] += delta; v_b -= delta; } else { m_b -= delta; }
            }
            __threadfence_block();
            j0 = j1;
            if (p[j0] == 0) break;
        }
        if (lane == 0) {
            int jj = j0;
            while (jj) { int jn = way[jj]; p[jj] = p[jn]; jj = jn; }
        }
        __syncthreads();
    }

    if (lane == 0) {
        int* ob = out + b * 2 * T_;
        int k = 0;
        for (int j = 1; j <= NHUN; ++j) {
            if (p[j] != 0) { ob[k] = j - 1; ob[T_ + k] = p[j] - 1; ++k; }
        }
    }
}

extern "C" void kernel_launch(void* const* d_in, const int* in_sizes, int n_in,
                              void* d_out, int out_size, void* d_ws, size_t ws_size,
                              hipStream_t stream) {
    const float* mq     = (const float*)d_in[0];   // [2,100,256,256]
    const float* cl     = (const float*)d_in[1];   // [2,100,134]
    const float* ml     = (const float*)d_in[2];   // [2,20,512,512]
    const int*   labels = (const int*)d_in[3];     // [2,20]
    int* out = (int*)d_out;                        // [2,2,20] int32
    float* ws = (float*)d_ws;

    float* lab_ps = ws + LABPS_OFF;
    float* cc     = ws + CC_OFF;
    float* cost   = ws + COST_OFF;

    size_t need = (size_t)WS_END_F * 4;

    if (ws_size >= need) {
        unsigned short* labF1 = (unsigned short*)(ws + LABF1_F);
        unsigned short* labF2 = (unsigned short*)(ws + LABF2_F);
        float* part = ws + PART_OFF;
        float* Csum = ws + CSUM_OFF;
        hipLaunchKernelGGL(lab_prep_kernel,   dim3(B_, NSL),  dim3(256), 0, stream,
                           ml, labF1, labF2, lab_ps, 1);
        hipLaunchKernelGGL(focal_mfma_kernel, dim3(B_ * KSB * MT_), dim3(256), 0, stream,
                           mq, labF1, labF2, part);
        hipLaunchKernelGGL(reduce_part_kernel, dim3(B_ * MT_, 33), dim3(256), 0, stream,
                           part, Csum);
        hipLaunchKernelGGL(compose_kernel,    dim3(B_ * MT_),  dim3(320), 0, stream,
                           Csum, cl, labels, lab_ps, cost);
    } else {
        hipLaunchKernelGGL(lab_prep_kernel,   dim3(B_, NSL),  dim3(256), 0, stream,
                           ml, (unsigned short*)ws, (unsigned short*)ws, lab_ps, 0);
        hipLaunchKernelGGL(class_cost_kernel, dim3(B_ * Q_),   dim3(64),  0, stream, cl, labels, cc);
        hipLaunchKernelGGL(mask_cost_mono_kernel, dim3(B_ * Q_), dim3(1024), 0, stream,
                           mq, ml, cc, lab_ps, cost);
    }
    hipLaunchKernelGGL(hungarian_kernel, dim3(B_), dim3(64), 0, stream, cost, out);
}